// Round 1
// baseline (218.050 us; speedup 1.0000x reference)
//
#include <hip/hip_runtime.h>
#include <math.h>

#define IMG_H 448
#define IMG_W 800
#define GRIDN 224
#define NCAM 6
#define NBOX 48
#define NPAIR (NCAM * NBOX)
#define NCLASS 10
#define FEATD 768
#define POOLD 588

// ws layout (floats):
//  [0, NPAIR*4)                      : per-pair {x1, y1, sq, vis}
//  [NPAIR*4, NPAIR*4 + NPAIR*10)     : per-pair softmax probs (zeroed each call)
//  [NPAIR*4 + NPAIR*10, +10)         : text feature norms
#define WS_PAIR 0
#define WS_PROBS (NPAIR * 4)
#define WS_TNORM (NPAIR * 4 + NPAIR * NCLASS)

__global__ void prep_kernel(const float* __restrict__ boxes7,
                            const float* __restrict__ l2i,
                            const float* __restrict__ img_aug,
                            const float* __restrict__ lidar_aug,
                            const float* __restrict__ text,
                            float* __restrict__ ws) {
    int tid = threadIdx.x;
    // zero the per-pair probs accumulator region (deterministic init each call)
    float* probs = ws + WS_PROBS;
    for (int i = tid; i < NPAIR * NCLASS; i += blockDim.x) probs[i] = 0.0f;
    // text norms
    if (tid < NCLASS) {
        float s = 0.f;
        for (int d = 0; d < FEATD; ++d) { float v = text[tid * FEATD + d]; s += v * v; }
        ws[WS_TNORM + tid] = sqrtf(s);
    }
    if (tid >= NPAIR) return;
    int cam = tid / NBOX, box = tid % NBOX;

    // inverse of lidar_aug[:3,:3] (general 3x3 inverse; identity in practice)
    float R[9];
    for (int i = 0; i < 3; ++i)
        for (int j = 0; j < 3; ++j) R[i * 3 + j] = lidar_aug[i * 4 + j];
    float ltx = lidar_aug[3], lty = lidar_aug[7], ltz = lidar_aug[11];
    float det = R[0] * (R[4] * R[8] - R[5] * R[7]) - R[1] * (R[3] * R[8] - R[5] * R[6]) +
                R[2] * (R[3] * R[7] - R[4] * R[6]);
    float inv[9];
    inv[0] = (R[4] * R[8] - R[5] * R[7]) / det;
    inv[1] = (R[2] * R[7] - R[1] * R[8]) / det;
    inv[2] = (R[1] * R[5] - R[2] * R[4]) / det;
    inv[3] = (R[5] * R[6] - R[3] * R[8]) / det;
    inv[4] = (R[0] * R[8] - R[2] * R[6]) / det;
    inv[5] = (R[2] * R[3] - R[0] * R[5]) / det;
    inv[6] = (R[3] * R[7] - R[4] * R[6]) / det;
    inv[7] = (R[1] * R[6] - R[0] * R[7]) / det;
    inv[8] = (R[0] * R[4] - R[1] * R[3]) / det;

    const float* M = l2i + cam * 16;      // rows of 4
    const float* A = img_aug + cam * 16;  // rows of 4
    const float* bx = boxes7 + box * 7;
    float cx = bx[0], cy = bx[1], cz = bx[2];
    float dx = bx[3], dy = bx[4], dz = bx[5], hd = bx[6];
    float ch = cosf(hd), sh = sinf(hd);
    const float tmpl[8][3] = {{.5f, .5f, -.5f},  {.5f, -.5f, -.5f}, {-.5f, -.5f, -.5f},
                              {-.5f, .5f, -.5f}, {.5f, .5f, .5f},   {.5f, -.5f, .5f},
                              {-.5f, -.5f, .5f}, {-.5f, .5f, .5f}};
    int minr = 0x7FFFFFFF, maxr = -0x7FFFFFFF - 1;
    int minc = 0x7FFFFFFF, maxc = -0x7FFFFFFF - 1;
    bool vis = false;
    for (int k = 0; k < 8; ++k) {
        float lx = dx * tmpl[k][0], ly = dy * tmpl[k][1], lz = dz * tmpl[k][2];
        // rotate: corner @ rot  (rot rows: (c,s,0), (-s,c,0), (0,0,1))
        float wxr = lx * ch - ly * sh;
        float wyr = lx * sh + ly * ch;
        float wzr = lz;
        float wx = wxr + cx, wy = wyr + cy, wz = wzr + cz;
        // lidar aug inverse
        float px_ = wx - ltx, py_ = wy - lty, pz_ = wz - ltz;
        float qx = inv[0] * px_ + inv[1] * py_ + inv[2] * pz_;
        float qy = inv[3] * px_ + inv[4] * py_ + inv[5] * pz_;
        float qz = inv[6] * px_ + inv[7] * py_ + inv[8] * pz_;
        // lidar2image
        float p0 = M[0] * qx + M[1] * qy + M[2] * qz + M[3];
        float p1 = M[4] * qx + M[5] * qy + M[6] * qz + M[7];
        float p2 = M[8] * qx + M[9] * qy + M[10] * qz + M[11];
        float zc = fminf(fmaxf(p2, 1e-5f), 1e5f);
        float sx = p0 / zc, sy = p1 / zc;
        // img aug
        float q0 = A[0] * sx + A[1] * sy + A[2] * zc + A[3];
        float q1 = A[4] * sx + A[5] * sy + A[6] * zc + A[7];
        float row = q1, col = q0;
        bool on = (row < (float)IMG_H) && (row >= 0.f) && (col < (float)IMG_W) && (col >= 0.f);
        vis = vis || on;
        int ri = (int)row;  // v_cvt_i32_f32: trunc toward zero, saturating
        int ci = (int)col;
        minr = min(minr, ri); maxr = max(maxr, ri);
        minc = min(minc, ci); maxc = max(maxc, ci);
    }
    int x1 = min(max(minc, 0), IMG_W);
    int x2 = min(max(maxc, 0), IMG_W);
    int y1 = min(max(minr, 0), IMG_H);
    int y2 = min(max(maxr, 0), IMG_H);
    int side = max(x2 - x1, y2 - y1);
    float sq = fmaxf((float)side, 64.0f);
    float* pw = ws + WS_PAIR + tid * 4;
    pw[0] = (float)x1;
    pw[1] = (float)y1;
    pw[2] = sq;
    pw[3] = vis ? 1.0f : 0.0f;
}

__global__ void __launch_bounds__(256) sample_head_kernel(
    const float* __restrict__ imgs, const float* __restrict__ W,
    const float* __restrict__ text, const float* __restrict__ ls_ptr,
    float* __restrict__ ws) {
    int pair = blockIdx.x;
    const float* pw = ws + WS_PAIR + pair * 4;
    if (pw[3] == 0.f) return;  // invisible: probs stay zero (masked in reference)
    float bx1 = pw[0], by1 = pw[1], sq = pw[2];
    int cam = pair / NBOX;
    const float* img = imgs + (size_t)cam * 3 * IMG_H * IMG_W;
    int tid = threadIdx.x;

    __shared__ float pooled[POOLD];

    // ---- phase 1: bilinear sample + 16x16 pool (separable: thread = grid column) ----
    float acc[3][14];
    for (int a = 0; a < 3; ++a)
        for (int b = 0; b < 14; ++b) acc[a][b] = 0.f;

    const float ustep = 1.0f / 223.0f;
    bool active = tid < GRIDN;
    float wx0 = 0.f, wx1 = 0.f, mx0 = 0.f, mx1 = 0.f;
    int xi0 = 0, xi1 = 0;
    if (active) {
        float u = (float)tid * ustep;
        float px = bx1 + sq * u;
        float gx = px / (float)IMG_W * 2.0f - 1.0f;
        float ix = ((gx + 1.0f) * (float)IMG_W - 1.0f) / 2.0f;
        float x0f = floorf(ix);
        wx1 = ix - x0f;
        wx0 = 1.0f - wx1;
        float x1f = x0f + 1.0f;
        mx0 = (x0f >= 0.f && x0f <= (float)(IMG_W - 1)) ? 1.f : 0.f;
        mx1 = (x1f >= 0.f && x1f <= (float)(IMG_W - 1)) ? 1.f : 0.f;
        xi0 = min(max((int)x0f, 0), IMG_W - 1);
        xi1 = min(max((int)x1f, 0), IMG_W - 1);
    }
    for (int i = 0; i < GRIDN; ++i) {
        float u = (float)i * ustep;
        float py = by1 + sq * u;
        float gy = py / (float)IMG_H * 2.0f - 1.0f;
        float iy = ((gy + 1.0f) * (float)IMG_H - 1.0f) / 2.0f;
        float y0f = floorf(iy);
        float wy1 = iy - y0f;
        float wy0 = 1.0f - wy1;
        float y1f = y0f + 1.0f;
        float my0 = (y0f >= 0.f && y0f <= (float)(IMG_H - 1)) ? 1.f : 0.f;
        float my1 = (y1f >= 0.f && y1f <= (float)(IMG_H - 1)) ? 1.f : 0.f;
        int yi0 = min(max((int)y0f, 0), IMG_H - 1);
        int yi1 = min(max((int)y1f, 0), IMG_H - 1);
        if (active) {
            int r0 = yi0 * IMG_W, r1 = yi1 * IMG_W;
            float w00 = wx0 * wy0, w10 = wx1 * wy0, w01 = wx0 * wy1, w11 = wx1 * wy1;
            float m00 = mx0 * my0, m10 = mx1 * my0, m01 = mx0 * my1, m11 = mx1 * my1;
            int pr = i >> 4;
            for (int c = 0; c < 3; ++c) {
                const float* ip = img + (size_t)c * (IMG_H * IMG_W);
                float g00 = ip[r0 + xi0] * m00;
                float g10 = ip[r0 + xi1] * m10;
                float g01 = ip[r1 + xi0] * m01;
                float g11 = ip[r1 + xi1] * m11;
                float v = g00 * w00 + g10 * w10 + g01 * w01 + g11 * w11;
                acc[c][pr] += v;
            }
        }
    }
    // reduce 16 columns -> one pooled cell, via xor butterfly within 16-lane groups
    for (int off = 8; off >= 1; off >>= 1)
        for (int c = 0; c < 3; ++c)
            for (int p = 0; p < 14; ++p) acc[c][p] += __shfl_xor(acc[c][p], off, 16);
    if (active && (tid & 15) == 0) {
        int pj = tid >> 4;
        for (int c = 0; c < 3; ++c)
            for (int p = 0; p < 14; ++p)
                pooled[c * 196 + p * 14 + pj] = acc[c][p] * (1.0f / 256.0f);
    }
    __syncthreads();

    // ---- phase 2: feats = pooled @ W (588x768), norm, 10-class logits, softmax ----
    float f0 = 0.f, f1 = 0.f, f2 = 0.f;
    {
        int d0 = tid, d1 = tid + 256, d2 = tid + 512;
        for (int k = 0; k < POOLD; ++k) {
            float p = pooled[k];
            const float* wr = W + (size_t)k * FEATD;
            f0 += p * wr[d0];
            f1 += p * wr[d1];
            f2 += p * wr[d2];
        }
    }
    float pn = f0 * f0 + f1 * f1 + f2 * f2;
    float pl[NCLASS];
    for (int k = 0; k < NCLASS; ++k) {
        const float* tr = text + (size_t)k * FEATD;
        pl[k] = f0 * tr[tid] + f1 * tr[tid + 256] + f2 * tr[tid + 512];
    }
    // wave(64) butterfly reduce
    for (int off = 32; off >= 1; off >>= 1) {
        pn += __shfl_xor(pn, off);
        for (int k = 0; k < NCLASS; ++k) pl[k] += __shfl_xor(pl[k], off);
    }
    __shared__ float rn[4];
    __shared__ float rl[4][NCLASS];
    int wave = tid >> 6, lane = tid & 63;
    if (lane == 0) {
        rn[wave] = pn;
        for (int k = 0; k < NCLASS; ++k) rl[wave][k] = pl[k];
    }
    __syncthreads();
    if (tid == 0) {
        float n2 = rn[0] + rn[1] + rn[2] + rn[3];
        float nrm = sqrtf(n2);
        float scale = expf(ls_ptr[0]);
        const float* tn = ws + WS_TNORM;
        float lg[NCLASS], m = -1e30f;
        for (int k = 0; k < NCLASS; ++k) {
            float d = rl[0][k] + rl[1][k] + rl[2][k] + rl[3][k];
            lg[k] = scale * (d / (nrm * tn[k]));
            m = fmaxf(m, lg[k]);
        }
        float s = 0.f;
        for (int k = 0; k < NCLASS; ++k) {
            lg[k] = expf(lg[k] - m);
            s += lg[k];
        }
        float* probs = ws + WS_PROBS + pair * NCLASS;
        for (int k = 0; k < NCLASS; ++k) probs[k] = lg[k] / s;
    }
}

__global__ void finalize_kernel(const int* __restrict__ gt, const float* __restrict__ ws,
                                float* __restrict__ out) {
    int n = threadIdx.x;
    bool match = false;
    if (n < NBOX) {
        const float* probs = ws + WS_PROBS;
        float cnt = 0.f;
        for (int c = 0; c < NCAM; ++c)
            cnt += (ws[WS_PAIR + (c * NBOX + n) * 4 + 3] != 0.f) ? 1.f : 0.f;
        float denom = fmaxf(cnt, 1.0f);
        float mp[NCLASS];
        for (int k = 0; k < NCLASS; ++k) {
            float s = 0.f;
            for (int c = 0; c < NCAM; ++c) s += probs[(c * NBOX + n) * NCLASS + k];
            mp[k] = s / denom;
            out[97 + n * NCLASS + k] = mp[k];
        }
        float best = mp[0];
        int pred = 0;
        for (int k = 1; k < NCLASS; ++k)
            if (mp[k] > best) { best = mp[k]; pred = k; }
        int tr = gt[n] - 1;
        out[n] = (float)pred;
        out[NBOX + n] = (float)tr;
        match = (pred == tr);
    }
    unsigned long long b = __ballot(match);
    if (n == 0) out[2 * NBOX] = (float)__popcll(b) / (float)NBOX;
}

extern "C" void kernel_launch(void* const* d_in, const int* in_sizes, int n_in,
                              void* d_out, int out_size, void* d_ws, size_t ws_size,
                              hipStream_t stream) {
    const float* boxes7 = (const float*)d_in[0];
    const int* gt = (const int*)d_in[1];
    const float* imgs = (const float*)d_in[2];
    const float* l2i = (const float*)d_in[3];
    const float* img_aug = (const float*)d_in[4];
    const float* lidar_aug = (const float*)d_in[5];
    const float* W = (const float*)d_in[6];
    const float* text = (const float*)d_in[7];
    const float* ls = (const float*)d_in[8];
    float* ws = (float*)d_ws;
    float* out = (float*)d_out;

    prep_kernel<<<1, 320, 0, stream>>>(boxes7, l2i, img_aug, lidar_aug, text, ws);
    sample_head_kernel<<<NPAIR, 256, 0, stream>>>(imgs, W, text, ls, ws);
    finalize_kernel<<<1, 64, 0, stream>>>(gt, ws, out);
}

// Round 2
// 74.471 us; speedup vs baseline: 2.9280x; 2.9280x over previous
//
#include <hip/hip_runtime.h>
#include <math.h>

#define IMG_H 448
#define IMG_W 800
#define GRIDN 224
#define NCAM 6
#define NBOX 48
#define NPAIR (NCAM * NBOX)
#define NCLASS 10
#define FEATD 768
#define POOLD 588
#define PROWS 14

// ws layout (floats):
//  WS_PAIR  [0, 288*4)        per-pair {x1, y1, sq, vis}
//  WS_TNORM [+1152, +10)      text feature norms
//  WS_POOL  [+1162, 288*588)  pooled features per pair
//  WS_PROBS [+170506, 288*10) per-pair softmax probs
#define WS_PAIR 0
#define WS_TNORM (NPAIR * 4)
#define WS_POOL (WS_TNORM + NCLASS)
#define WS_PROBS (WS_POOL + NPAIR * POOLD)

__global__ void prep_kernel(const float* __restrict__ boxes7,
                            const float* __restrict__ l2i,
                            const float* __restrict__ img_aug,
                            const float* __restrict__ lidar_aug,
                            const float* __restrict__ text,
                            float* __restrict__ ws) {
    int tid = threadIdx.x;
    // text norms
    if (tid < NCLASS) {
        float s = 0.f;
        for (int d = 0; d < FEATD; ++d) { float v = text[tid * FEATD + d]; s += v * v; }
        ws[WS_TNORM + tid] = sqrtf(s);
    }
    if (tid >= NPAIR) return;
    int cam = tid / NBOX, box = tid % NBOX;

    // inverse of lidar_aug[:3,:3] (general 3x3 inverse; identity in practice)
    float R[9];
    for (int i = 0; i < 3; ++i)
        for (int j = 0; j < 3; ++j) R[i * 3 + j] = lidar_aug[i * 4 + j];
    float ltx = lidar_aug[3], lty = lidar_aug[7], ltz = lidar_aug[11];
    float det = R[0] * (R[4] * R[8] - R[5] * R[7]) - R[1] * (R[3] * R[8] - R[5] * R[6]) +
                R[2] * (R[3] * R[7] - R[4] * R[6]);
    float inv[9];
    inv[0] = (R[4] * R[8] - R[5] * R[7]) / det;
    inv[1] = (R[2] * R[7] - R[1] * R[8]) / det;
    inv[2] = (R[1] * R[5] - R[2] * R[4]) / det;
    inv[3] = (R[5] * R[6] - R[3] * R[8]) / det;
    inv[4] = (R[0] * R[8] - R[2] * R[6]) / det;
    inv[5] = (R[2] * R[3] - R[0] * R[5]) / det;
    inv[6] = (R[3] * R[7] - R[4] * R[6]) / det;
    inv[7] = (R[1] * R[6] - R[0] * R[7]) / det;
    inv[8] = (R[0] * R[4] - R[1] * R[3]) / det;

    const float* M = l2i + cam * 16;
    const float* A = img_aug + cam * 16;
    const float* bx = boxes7 + box * 7;
    float cx = bx[0], cy = bx[1], cz = bx[2];
    float dx = bx[3], dy = bx[4], dz = bx[5], hd = bx[6];
    float ch = cosf(hd), sh = sinf(hd);
    const float tmpl[8][3] = {{.5f, .5f, -.5f},  {.5f, -.5f, -.5f}, {-.5f, -.5f, -.5f},
                              {-.5f, .5f, -.5f}, {.5f, .5f, .5f},   {.5f, -.5f, .5f},
                              {-.5f, -.5f, .5f}, {-.5f, .5f, .5f}};
    int minr = 0x7FFFFFFF, maxr = -0x7FFFFFFF - 1;
    int minc = 0x7FFFFFFF, maxc = -0x7FFFFFFF - 1;
    bool vis = false;
    for (int k = 0; k < 8; ++k) {
        float lx = dx * tmpl[k][0], ly = dy * tmpl[k][1], lz = dz * tmpl[k][2];
        float wxr = lx * ch - ly * sh;
        float wyr = lx * sh + ly * ch;
        float wzr = lz;
        float wx = wxr + cx, wy = wyr + cy, wz = wzr + cz;
        float px_ = wx - ltx, py_ = wy - lty, pz_ = wz - ltz;
        float qx = inv[0] * px_ + inv[1] * py_ + inv[2] * pz_;
        float qy = inv[3] * px_ + inv[4] * py_ + inv[5] * pz_;
        float qz = inv[6] * px_ + inv[7] * py_ + inv[8] * pz_;
        float p0 = M[0] * qx + M[1] * qy + M[2] * qz + M[3];
        float p1 = M[4] * qx + M[5] * qy + M[6] * qz + M[7];
        float p2 = M[8] * qx + M[9] * qy + M[10] * qz + M[11];
        float zc = fminf(fmaxf(p2, 1e-5f), 1e5f);
        float sx = p0 / zc, sy = p1 / zc;
        float q0 = A[0] * sx + A[1] * sy + A[2] * zc + A[3];
        float q1 = A[4] * sx + A[5] * sy + A[6] * zc + A[7];
        float row = q1, col = q0;
        bool on = (row < (float)IMG_H) && (row >= 0.f) && (col < (float)IMG_W) && (col >= 0.f);
        vis = vis || on;
        int ri = (int)row;
        int ci = (int)col;
        minr = min(minr, ri); maxr = max(maxr, ri);
        minc = min(minc, ci); maxc = max(maxc, ci);
    }
    int x1 = min(max(minc, 0), IMG_W);
    int x2 = min(max(maxc, 0), IMG_W);
    int y1 = min(max(minr, 0), IMG_H);
    int y2 = min(max(maxr, 0), IMG_H);
    int side = max(x2 - x1, y2 - y1);
    float sq = fmaxf((float)side, 64.0f);
    float* pw = ws + WS_PAIR + tid * 4;
    pw[0] = (float)x1;
    pw[1] = (float)y1;
    pw[2] = sq;
    pw[3] = vis ? 1.0f : 0.0f;
}

// One block per (pair, pooled-row). 256 threads; thread = grid column (224 active).
__global__ void __launch_bounds__(256) pool_kernel(const float* __restrict__ imgs,
                                                   float* __restrict__ ws) {
    int pair = blockIdx.x / PROWS;
    int pr = blockIdx.x % PROWS;
    const float* pw = ws + WS_PAIR + pair * 4;
    if (pw[3] == 0.f) return;  // invisible: pooled never consumed
    float bx1 = pw[0], by1 = pw[1], sq = pw[2];
    int cam = pair / NBOX;
    const float* img = imgs + (size_t)cam * 3 * IMG_H * IMG_W;
    int tid = threadIdx.x;
    bool active = tid < GRIDN;

    const float ustep = 1.0f / 223.0f;
    float wx0 = 0.f, wx1 = 0.f, mx0 = 0.f, mx1 = 0.f;
    int xi0 = 0, xi1 = 0;
    if (active) {
        float u = (float)tid * ustep;
        float px = bx1 + sq * u;
        float gx = px / (float)IMG_W * 2.0f - 1.0f;
        float ix = ((gx + 1.0f) * (float)IMG_W - 1.0f) / 2.0f;
        float x0f = floorf(ix);
        wx1 = ix - x0f;
        wx0 = 1.0f - wx1;
        float x1f = x0f + 1.0f;
        mx0 = (x0f >= 0.f && x0f <= (float)(IMG_W - 1)) ? 1.f : 0.f;
        mx1 = (x1f >= 0.f && x1f <= (float)(IMG_W - 1)) ? 1.f : 0.f;
        xi0 = min(max((int)x0f, 0), IMG_W - 1);
        xi1 = min(max((int)x1f, 0), IMG_W - 1);
    }
    float acc0 = 0.f, acc1 = 0.f, acc2 = 0.f;
    for (int r = 0; r < 16; ++r) {
        int i = pr * 16 + r;
        float u = (float)i * ustep;
        float py = by1 + sq * u;
        float gy = py / (float)IMG_H * 2.0f - 1.0f;
        float iy = ((gy + 1.0f) * (float)IMG_H - 1.0f) / 2.0f;
        float y0f = floorf(iy);
        float wy1 = iy - y0f;
        float wy0 = 1.0f - wy1;
        float y1f = y0f + 1.0f;
        float my0 = (y0f >= 0.f && y0f <= (float)(IMG_H - 1)) ? 1.f : 0.f;
        float my1 = (y1f >= 0.f && y1f <= (float)(IMG_H - 1)) ? 1.f : 0.f;
        int yi0 = min(max((int)y0f, 0), IMG_H - 1);
        int yi1 = min(max((int)y1f, 0), IMG_H - 1);
        if (active) {
            int r0 = yi0 * IMG_W, r1 = yi1 * IMG_W;
            float w00 = wx0 * wy0, w10 = wx1 * wy0, w01 = wx0 * wy1, w11 = wx1 * wy1;
            float m00 = mx0 * my0, m10 = mx1 * my0, m01 = mx0 * my1, m11 = mx1 * my1;
            {
                const float* ip = img;
                float v = ip[r0 + xi0] * m00 * w00 + ip[r0 + xi1] * m10 * w10 +
                          ip[r1 + xi0] * m01 * w01 + ip[r1 + xi1] * m11 * w11;
                acc0 += v;
            }
            {
                const float* ip = img + (size_t)(IMG_H * IMG_W);
                float v = ip[r0 + xi0] * m00 * w00 + ip[r0 + xi1] * m10 * w10 +
                          ip[r1 + xi0] * m01 * w01 + ip[r1 + xi1] * m11 * w11;
                acc1 += v;
            }
            {
                const float* ip = img + (size_t)(2 * IMG_H * IMG_W);
                float v = ip[r0 + xi0] * m00 * w00 + ip[r0 + xi1] * m10 * w10 +
                          ip[r1 + xi0] * m01 * w01 + ip[r1 + xi1] * m11 * w11;
                acc2 += v;
            }
        }
    }
    // reduce 16 grid-columns -> one pooled cell
    for (int off = 8; off >= 1; off >>= 1) {
        acc0 += __shfl_xor(acc0, off, 16);
        acc1 += __shfl_xor(acc1, off, 16);
        acc2 += __shfl_xor(acc2, off, 16);
    }
    if (active && (tid & 15) == 0) {
        int pj = tid >> 4;
        float* pool = ws + WS_POOL + (size_t)pair * POOLD;
        pool[0 * 196 + pr * 14 + pj] = acc0 * (1.0f / 256.0f);
        pool[1 * 196 + pr * 14 + pj] = acc1 * (1.0f / 256.0f);
        pool[2 * 196 + pr * 14 + pj] = acc2 * (1.0f / 256.0f);
    }
}

__global__ void __launch_bounds__(256) head_kernel(const float* __restrict__ W,
                                                   const float* __restrict__ text,
                                                   const float* __restrict__ ls_ptr,
                                                   float* __restrict__ ws) {
    int pair = blockIdx.x;
    int tid = threadIdx.x;
    const float* pw = ws + WS_PAIR + pair * 4;
    if (pw[3] == 0.f) {  // invisible: probs = 0 (masked in reference)
        if (tid < NCLASS) ws[WS_PROBS + pair * NCLASS + tid] = 0.f;
        return;
    }
    __shared__ float pooled[POOLD];
    for (int i = tid; i < POOLD; i += 256) pooled[i] = ws[WS_POOL + (size_t)pair * POOLD + i];
    __syncthreads();

    float f0 = 0.f, f1 = 0.f, f2 = 0.f;
    for (int k = 0; k < POOLD; ++k) {
        float p = pooled[k];
        const float* wr = W + (size_t)k * FEATD;
        f0 += p * wr[tid];
        f1 += p * wr[tid + 256];
        f2 += p * wr[tid + 512];
    }
    float pn = f0 * f0 + f1 * f1 + f2 * f2;
    float pl[NCLASS];
    for (int k = 0; k < NCLASS; ++k) {
        const float* tr = text + (size_t)k * FEATD;
        pl[k] = f0 * tr[tid] + f1 * tr[tid + 256] + f2 * tr[tid + 512];
    }
    for (int off = 32; off >= 1; off >>= 1) {
        pn += __shfl_xor(pn, off);
        for (int k = 0; k < NCLASS; ++k) pl[k] += __shfl_xor(pl[k], off);
    }
    __shared__ float rn[4];
    __shared__ float rl[4][NCLASS];
    int wave = tid >> 6, lane = tid & 63;
    if (lane == 0) {
        rn[wave] = pn;
        for (int k = 0; k < NCLASS; ++k) rl[wave][k] = pl[k];
    }
    __syncthreads();
    if (tid == 0) {
        float n2 = rn[0] + rn[1] + rn[2] + rn[3];
        float nrm = sqrtf(n2);
        float scale = expf(ls_ptr[0]);
        const float* tn = ws + WS_TNORM;
        float lg[NCLASS], m = -1e30f;
        for (int k = 0; k < NCLASS; ++k) {
            float d = rl[0][k] + rl[1][k] + rl[2][k] + rl[3][k];
            lg[k] = scale * (d / (nrm * tn[k]));
            m = fmaxf(m, lg[k]);
        }
        float s = 0.f;
        for (int k = 0; k < NCLASS; ++k) {
            lg[k] = expf(lg[k] - m);
            s += lg[k];
        }
        float* probs = ws + WS_PROBS + pair * NCLASS;
        for (int k = 0; k < NCLASS; ++k) probs[k] = lg[k] / s;
    }
}

__global__ void finalize_kernel(const int* __restrict__ gt, const float* __restrict__ ws,
                                float* __restrict__ out) {
    int n = threadIdx.x;
    bool match = false;
    if (n < NBOX) {
        const float* probs = ws + WS_PROBS;
        float cnt = 0.f;
        for (int c = 0; c < NCAM; ++c)
            cnt += (ws[WS_PAIR + (c * NBOX + n) * 4 + 3] != 0.f) ? 1.f : 0.f;
        float denom = fmaxf(cnt, 1.0f);
        float mp[NCLASS];
        for (int k = 0; k < NCLASS; ++k) {
            float s = 0.f;
            for (int c = 0; c < NCAM; ++c) s += probs[(c * NBOX + n) * NCLASS + k];
            mp[k] = s / denom;
            out[97 + n * NCLASS + k] = mp[k];
        }
        float best = mp[0];
        int pred = 0;
        for (int k = 1; k < NCLASS; ++k)
            if (mp[k] > best) { best = mp[k]; pred = k; }
        int tr = gt[n] - 1;
        out[n] = (float)pred;
        out[NBOX + n] = (float)tr;
        match = (pred == tr);
    }
    unsigned long long b = __ballot(match);
    if (n == 0) out[2 * NBOX] = (float)__popcll(b) / (float)NBOX;
}

extern "C" void kernel_launch(void* const* d_in, const int* in_sizes, int n_in,
                              void* d_out, int out_size, void* d_ws, size_t ws_size,
                              hipStream_t stream) {
    const float* boxes7 = (const float*)d_in[0];
    const int* gt = (const int*)d_in[1];
    const float* imgs = (const float*)d_in[2];
    const float* l2i = (const float*)d_in[3];
    const float* img_aug = (const float*)d_in[4];
    const float* lidar_aug = (const float*)d_in[5];
    const float* W = (const float*)d_in[6];
    const float* text = (const float*)d_in[7];
    const float* ls = (const float*)d_in[8];
    float* ws = (float*)d_ws;
    float* out = (float*)d_out;

    prep_kernel<<<1, 320, 0, stream>>>(boxes7, l2i, img_aug, lidar_aug, text, ws);
    pool_kernel<<<NPAIR * PROWS, 256, 0, stream>>>(imgs, ws);
    head_kernel<<<NPAIR, 256, 0, stream>>>(W, text, ls, ws);
    finalize_kernel<<<1, 64, 0, stream>>>(gt, ws, out);
}

// Round 4
// 54.307 us; speedup vs baseline: 4.0151x; 1.3713x over previous
//
#include <hip/hip_runtime.h>
#include <math.h>

#define IMG_H 448
#define IMG_W 800
#define GRIDN 224
#define NCAM 6
#define NBOX 48
#define NPAIR (NCAM * NBOX)
#define NCLASS 10
#define FEATD 768
#define POOLD 588
#define PROWS 14
#define KSPLIT 4
#define KCH 147  // 588 / 4

// ws layout (floats):
//  WS_PAIR  [0, 288*4)         per-pair {x1, y1, sq, vis}
//  WS_TNORM [+1152, +10)       text feature norms
//  WS_POOL  288*588            pooled features per pair
//  WS_FEAT  288*4*768          partial feature sums (K-split)
//  WS_PROBS 288*10             per-pair softmax probs
#define WS_PAIR 0
#define WS_TNORM (NPAIR * 4)
#define WS_POOL (WS_TNORM + NCLASS)
#define WS_FEAT (WS_POOL + NPAIR * POOLD)
#define WS_PROBS (WS_FEAT + NPAIR * KSPLIT * FEATD)

__global__ void prep_kernel(const float* __restrict__ boxes7,
                            const float* __restrict__ l2i,
                            const float* __restrict__ img_aug,
                            const float* __restrict__ lidar_aug,
                            const float* __restrict__ text,
                            float* __restrict__ ws) {
    int tid = threadIdx.x;
    // text norms
    if (tid < NCLASS) {
        float s = 0.f;
        for (int d = 0; d < FEATD; ++d) { float v = text[tid * FEATD + d]; s += v * v; }
        ws[WS_TNORM + tid] = sqrtf(s);
    }
    if (tid >= NPAIR) return;
    int cam = tid / NBOX, box = tid % NBOX;

    // inverse of lidar_aug[:3,:3] (general 3x3 inverse; identity in practice)
    float R[9];
    for (int i = 0; i < 3; ++i)
        for (int j = 0; j < 3; ++j) R[i * 3 + j] = lidar_aug[i * 4 + j];
    float ltx = lidar_aug[3], lty = lidar_aug[7], ltz = lidar_aug[11];
    float det = R[0] * (R[4] * R[8] - R[5] * R[7]) - R[1] * (R[3] * R[8] - R[5] * R[6]) +
                R[2] * (R[3] * R[7] - R[4] * R[6]);
    float inv[9];
    inv[0] = (R[4] * R[8] - R[5] * R[7]) / det;
    inv[1] = (R[2] * R[7] - R[1] * R[8]) / det;
    inv[2] = (R[1] * R[5] - R[2] * R[4]) / det;
    inv[3] = (R[5] * R[6] - R[3] * R[8]) / det;
    inv[4] = (R[0] * R[8] - R[2] * R[6]) / det;
    inv[5] = (R[2] * R[3] - R[0] * R[5]) / det;
    inv[6] = (R[3] * R[7] - R[4] * R[6]) / det;
    inv[7] = (R[1] * R[6] - R[0] * R[7]) / det;
    inv[8] = (R[0] * R[4] - R[1] * R[3]) / det;

    const float* M = l2i + cam * 16;
    const float* A = img_aug + cam * 16;
    const float* bx = boxes7 + box * 7;
    float cx = bx[0], cy = bx[1], cz = bx[2];
    float dx = bx[3], dy = bx[4], dz = bx[5], hd = bx[6];
    float ch = cosf(hd), sh = sinf(hd);
    const float tmpl[8][3] = {{.5f, .5f, -.5f},  {.5f, -.5f, -.5f}, {-.5f, -.5f, -.5f},
                              {-.5f, .5f, -.5f}, {.5f, .5f, .5f},   {.5f, -.5f, .5f},
                              {-.5f, -.5f, .5f}, {-.5f, .5f, .5f}};
    int minr = 0x7FFFFFFF, maxr = -0x7FFFFFFF - 1;
    int minc = 0x7FFFFFFF, maxc = -0x7FFFFFFF - 1;
    bool vis = false;
    for (int k = 0; k < 8; ++k) {
        float lx = dx * tmpl[k][0], ly = dy * tmpl[k][1], lz = dz * tmpl[k][2];
        float wxr = lx * ch - ly * sh;
        float wyr = lx * sh + ly * ch;
        float wzr = lz;
        float wx = wxr + cx, wy = wyr + cy, wz = wzr + cz;
        float px_ = wx - ltx, py_ = wy - lty, pz_ = wz - ltz;
        float qx = inv[0] * px_ + inv[1] * py_ + inv[2] * pz_;
        float qy = inv[3] * px_ + inv[4] * py_ + inv[5] * pz_;
        float qz = inv[6] * px_ + inv[7] * py_ + inv[8] * pz_;
        float p0 = M[0] * qx + M[1] * qy + M[2] * qz + M[3];
        float p1 = M[4] * qx + M[5] * qy + M[6] * qz + M[7];
        float p2 = M[8] * qx + M[9] * qy + M[10] * qz + M[11];
        float zc = fminf(fmaxf(p2, 1e-5f), 1e5f);
        float sx = p0 / zc, sy = p1 / zc;
        float q0 = A[0] * sx + A[1] * sy + A[2] * zc + A[3];
        float q1 = A[4] * sx + A[5] * sy + A[6] * zc + A[7];
        float row = q1, col = q0;
        bool on = (row < (float)IMG_H) && (row >= 0.f) && (col < (float)IMG_W) && (col >= 0.f);
        vis = vis || on;
        int ri = (int)row;
        int ci = (int)col;
        minr = min(minr, ri); maxr = max(maxr, ri);
        minc = min(minc, ci); maxc = max(maxc, ci);
    }
    int x1 = min(max(minc, 0), IMG_W);
    int x2 = min(max(maxc, 0), IMG_W);
    int y1 = min(max(minr, 0), IMG_H);
    int y2 = min(max(maxr, 0), IMG_H);
    int side = max(x2 - x1, y2 - y1);
    float sq = fmaxf((float)side, 64.0f);
    float* pw = ws + WS_PAIR + tid * 4;
    pw[0] = (float)x1;
    pw[1] = (float)y1;
    pw[2] = sq;
    pw[3] = vis ? 1.0f : 0.0f;
}

// One block per (pair, pooled-row). 256 threads; thread = grid column (224 active).
__global__ void __launch_bounds__(256) pool_kernel(const float* __restrict__ imgs,
                                                   float* __restrict__ ws) {
    int pair = blockIdx.x / PROWS;
    int pr = blockIdx.x % PROWS;
    const float* pw = ws + WS_PAIR + pair * 4;
    if (pw[3] == 0.f) return;  // invisible: pooled never consumed
    float bx1 = pw[0], by1 = pw[1], sq = pw[2];
    int cam = pair / NBOX;
    const float* img = imgs + (size_t)cam * 3 * IMG_H * IMG_W;
    int tid = threadIdx.x;
    bool active = tid < GRIDN;

    const float ustep = 1.0f / 223.0f;
    float wx0 = 0.f, wx1 = 0.f, mx0 = 0.f, mx1 = 0.f;
    int xi0 = 0, xi1 = 0;
    if (active) {
        float u = (float)tid * ustep;
        float px = bx1 + sq * u;
        float gx = px / (float)IMG_W * 2.0f - 1.0f;
        float ix = ((gx + 1.0f) * (float)IMG_W - 1.0f) / 2.0f;
        float x0f = floorf(ix);
        wx1 = ix - x0f;
        wx0 = 1.0f - wx1;
        float x1f = x0f + 1.0f;
        mx0 = (x0f >= 0.f && x0f <= (float)(IMG_W - 1)) ? 1.f : 0.f;
        mx1 = (x1f >= 0.f && x1f <= (float)(IMG_W - 1)) ? 1.f : 0.f;
        xi0 = min(max((int)x0f, 0), IMG_W - 1);
        xi1 = min(max((int)x1f, 0), IMG_W - 1);
    }
    float acc0 = 0.f, acc1 = 0.f, acc2 = 0.f;
    for (int r = 0; r < 16; ++r) {
        int i = pr * 16 + r;
        float u = (float)i * ustep;
        float py = by1 + sq * u;
        float gy = py / (float)IMG_H * 2.0f - 1.0f;
        float iy = ((gy + 1.0f) * (float)IMG_H - 1.0f) / 2.0f;
        float y0f = floorf(iy);
        float wy1 = iy - y0f;
        float wy0 = 1.0f - wy1;
        float y1f = y0f + 1.0f;
        float my0 = (y0f >= 0.f && y0f <= (float)(IMG_H - 1)) ? 1.f : 0.f;
        float my1 = (y1f >= 0.f && y1f <= (float)(IMG_H - 1)) ? 1.f : 0.f;
        int yi0 = min(max((int)y0f, 0), IMG_H - 1);
        int yi1 = min(max((int)y1f, 0), IMG_H - 1);
        if (active) {
            int r0 = yi0 * IMG_W, r1 = yi1 * IMG_W;
            float w00 = wx0 * wy0, w10 = wx1 * wy0, w01 = wx0 * wy1, w11 = wx1 * wy1;
            float m00 = mx0 * my0, m10 = mx1 * my0, m01 = mx0 * my1, m11 = mx1 * my1;
            {
                const float* ip = img;
                float v = ip[r0 + xi0] * m00 * w00 + ip[r0 + xi1] * m10 * w10 +
                          ip[r1 + xi0] * m01 * w01 + ip[r1 + xi1] * m11 * w11;
                acc0 += v;
            }
            {
                const float* ip = img + (size_t)(IMG_H * IMG_W);
                float v = ip[r0 + xi0] * m00 * w00 + ip[r0 + xi1] * m10 * w10 +
                          ip[r1 + xi0] * m01 * w01 + ip[r1 + xi1] * m11 * w11;
                acc1 += v;
            }
            {
                const float* ip = img + (size_t)(2 * IMG_H * IMG_W);
                float v = ip[r0 + xi0] * m00 * w00 + ip[r0 + xi1] * m10 * w10 +
                          ip[r1 + xi0] * m01 * w01 + ip[r1 + xi1] * m11 * w11;
                acc2 += v;
            }
        }
    }
    // reduce 16 grid-columns -> one pooled cell
    for (int off = 8; off >= 1; off >>= 1) {
        acc0 += __shfl_xor(acc0, off, 16);
        acc1 += __shfl_xor(acc1, off, 16);
        acc2 += __shfl_xor(acc2, off, 16);
    }
    if (active && (tid & 15) == 0) {
        int pj = tid >> 4;
        float* pool = ws + WS_POOL + (size_t)pair * POOLD;
        pool[0 * 196 + pr * 14 + pj] = acc0 * (1.0f / 256.0f);
        pool[1 * 196 + pr * 14 + pj] = acc1 * (1.0f / 256.0f);
        pool[2 * 196 + pr * 14 + pj] = acc2 * (1.0f / 256.0f);
    }
}

// Partial GEMV: one block per (pair, K-chunk); 768 threads, thread = output dim.
__global__ void __launch_bounds__(768) head1_kernel(const float* __restrict__ W,
                                                    float* __restrict__ ws) {
    int pair = blockIdx.x / KSPLIT;
    int kc = blockIdx.x % KSPLIT;
    if (ws[WS_PAIR + pair * 4 + 3] == 0.f) return;  // invisible: partials unused
    int tid = threadIdx.x;
    __shared__ float pk[KCH];
    if (tid < KCH) pk[tid] = ws[WS_POOL + (size_t)pair * POOLD + kc * KCH + tid];
    __syncthreads();
    const float* Wp = W + (size_t)(kc * KCH) * FEATD + tid;
    float f = 0.f;
#pragma unroll 7
    for (int k = 0; k < KCH; ++k) f += pk[k] * Wp[(size_t)k * FEATD];
    ws[WS_FEAT + ((size_t)pair * KSPLIT + kc) * FEATD + tid] = f;
}

// Reduce K-partials, normalize, logits vs text, softmax. One block per pair.
__global__ void __launch_bounds__(256) head2_kernel(const float* __restrict__ text,
                                                    const float* __restrict__ ls_ptr,
                                                    float* __restrict__ ws) {
    int pair = blockIdx.x;
    int tid = threadIdx.x;
    const float* pw = ws + WS_PAIR + pair * 4;
    if (pw[3] == 0.f) {  // invisible: probs = 0 (masked in reference)
        if (tid < NCLASS) ws[WS_PROBS + pair * NCLASS + tid] = 0.f;
        return;
    }
    const float* fb = ws + WS_FEAT + (size_t)pair * KSPLIT * FEATD;
    float f0 = 0.f, f1 = 0.f, f2 = 0.f;
    for (int kc = 0; kc < KSPLIT; ++kc) {
        const float* fp = fb + (size_t)kc * FEATD;
        f0 += fp[tid];
        f1 += fp[tid + 256];
        f2 += fp[tid + 512];
    }
    float pn = f0 * f0 + f1 * f1 + f2 * f2;
    float pl[NCLASS];
    for (int k = 0; k < NCLASS; ++k) {
        const float* tr = text + (size_t)k * FEATD;
        pl[k] = f0 * tr[tid] + f1 * tr[tid + 256] + f2 * tr[tid + 512];
    }
    for (int off = 32; off >= 1; off >>= 1) {
        pn += __shfl_xor(pn, off);
        for (int k = 0; k < NCLASS; ++k) pl[k] += __shfl_xor(pl[k], off);
    }
    __shared__ float rn[4];
    __shared__ float rl[4][NCLASS];
    int wave = tid >> 6, lane = tid & 63;
    if (lane == 0) {
        rn[wave] = pn;
        for (int k = 0; k < NCLASS; ++k) rl[wave][k] = pl[k];
    }
    __syncthreads();
    if (tid == 0) {
        float n2 = rn[0] + rn[1] + rn[2] + rn[3];
        float nrm = sqrtf(n2);
        float scale = expf(ls_ptr[0]);
        const float* tn = ws + WS_TNORM;
        float lg[NCLASS], m = -1e30f;
        for (int k = 0; k < NCLASS; ++k) {
            float d = rl[0][k] + rl[1][k] + rl[2][k] + rl[3][k];
            lg[k] = scale * (d / (nrm * tn[k]));
            m = fmaxf(m, lg[k]);
        }
        float s = 0.f;
        for (int k = 0; k < NCLASS; ++k) {
            lg[k] = expf(lg[k] - m);
            s += lg[k];
        }
        float* probs = ws + WS_PROBS + pair * NCLASS;
        for (int k = 0; k < NCLASS; ++k) probs[k] = lg[k] / s;
    }
}

__global__ void finalize_kernel(const int* __restrict__ gt, const float* __restrict__ ws,
                                float* __restrict__ out) {
    int n = threadIdx.x;
    bool match = false;
    if (n < NBOX) {
        const float* probs = ws + WS_PROBS;
        float cnt = 0.f;
        for (int c = 0; c < NCAM; ++c)
            cnt += (ws[WS_PAIR + (c * NBOX + n) * 4 + 3] != 0.f) ? 1.f : 0.f;
        float denom = fmaxf(cnt, 1.0f);
        float mp[NCLASS];
        for (int k = 0; k < NCLASS; ++k) {
            float s = 0.f;
            for (int c = 0; c < NCAM; ++c) s += probs[(c * NBOX + n) * NCLASS + k];
            mp[k] = s / denom;
            out[97 + n * NCLASS + k] = mp[k];
        }
        float best = mp[0];
        int pred = 0;
        for (int k = 1; k < NCLASS; ++k)
            if (mp[k] > best) { best = mp[k]; pred = k; }
        int tr = gt[n] - 1;
        out[n] = (float)pred;
        out[NBOX + n] = (float)tr;
        match = (pred == tr);
    }
    unsigned long long b = __ballot(match);
    if (n == 0) out[2 * NBOX] = (float)__popcll(b) / (float)NBOX;
}

extern "C" void kernel_launch(void* const* d_in, const int* in_sizes, int n_in,
                              void* d_out, int out_size, void* d_ws, size_t ws_size,
                              hipStream_t stream) {
    const float* boxes7 = (const float*)d_in[0];
    const int* gt = (const int*)d_in[1];
    const float* imgs = (const float*)d_in[2];
    const float* l2i = (const float*)d_in[3];
    const float* img_aug = (const float*)d_in[4];
    const float* lidar_aug = (const float*)d_in[5];
    const float* W = (const float*)d_in[6];
    const float* text = (const float*)d_in[7];
    const float* ls = (const float*)d_in[8];
    float* ws = (float*)d_ws;
    float* out = (float*)d_out;

    prep_kernel<<<1, 320, 0, stream>>>(boxes7, l2i, img_aug, lidar_aug, text, ws);
    pool_kernel<<<NPAIR * PROWS, 256, 0, stream>>>(imgs, ws);
    head1_kernel<<<NPAIR * KSPLIT, 768, 0, stream>>>(W, ws);
    head2_kernel<<<NPAIR, 256, 0, stream>>>(text, ls, ws);
    finalize_kernel<<<1, 64, 0, stream>>>(gt, ws, out);
}